// Round 8
// baseline (636.673 us; speedup 1.0000x reference)
//
#include <hip/hip_runtime.h>
#include <hip/hip_bf16.h>

typedef _Float16 f16x8 __attribute__((ext_vector_type(8)));
typedef _Float16 f16x4 __attribute__((ext_vector_type(4)));
typedef float f32x4 __attribute__((ext_vector_type(4)));

__device__ __forceinline__ float tanh_fast(float x) {
  float e = __expf(2.0f * x);
  return 1.0f - 2.0f * __builtin_amdgcn_rcpf(e + 1.0f);
}
__device__ __forceinline__ float sigmoid_fast(float x) {
  return __builtin_amdgcn_rcpf(1.0f + __expf(-x));
}

// ---------------- K0: weight prep ----------------
// Fragment-major tiles of 512 halfwords: lane l elem j = B[k=kt*32+(l>>4)*8+j][col=nt*16+(l&15)].
// V1p: tile = nt (32 k only). V2p: tile = kt*64 + nt (kt-major). T1p: tile = kt*16 + nt.
// T2p: tile = nt*8 + kt (small, unchanged).
__global__ __launch_bounds__(256) void prep_weights(
    const float* __restrict__ W1, const float* __restrict__ W2,
    const float* __restrict__ Wq1, const float* __restrict__ Wq2,
    _Float16* __restrict__ V1p, _Float16* __restrict__ V2p,
    _Float16* __restrict__ T1p, _Float16* __restrict__ T2p) {
  __shared__ float S[32 * 33];
  int b = blockIdx.x, t = threadIdx.x;
  if (b < 2624) {
    const float* in; _Float16* out; int N, nc0, tile;
    if (b < 2048) {        // W2 [32][1024][32]: h, ntl, kt
      int h = b >> 6, rem = b & 63, ntl = rem >> 5, kt = rem & 31;
      in = W2 + (size_t)h * 32768 + (size_t)kt * 32 * 32;
      N = 32; nc0 = ntl * 16;
      out = V2p; tile = kt * 64 + (h * 2 + ntl);
    } else if (b < 2560) { // Wq1 [1024][256]
      int i = b - 2048, nt = i >> 5, kt = i & 31;
      in = Wq1 + (size_t)kt * 32 * 256; N = 256; nc0 = nt * 16;
      out = T1p; tile = kt * 16 + nt;
    } else {               // Wq2 [256][128]
      int i = b - 2560, nt = i >> 3, kt = i & 7;
      in = Wq2 + (size_t)kt * 32 * 128; N = 128; nc0 = nt * 16;
      out = T2p; tile = nt * 8 + kt;
    }
    if (t < 128) {
      int r = t >> 2, c4 = (t & 3) * 4;
      const float4 v = *(const float4*)(in + (size_t)r * N + nc0 + c4);
      S[r * 17 + c4 + 0] = v.x; S[r * 17 + c4 + 1] = v.y;
      S[r * 17 + c4 + 2] = v.z; S[r * 17 + c4 + 3] = v.w;
    }
    __syncthreads();
    if (t < 128) {
      int w2 = t >> 6, l = t & 63, q = l >> 4, l15 = l & 15;
      f16x4 o;
#pragma unroll
      for (int jj = 0; jj < 4; ++jj)
        o[jj] = (_Float16)S[(q * 8 + w2 * 4 + jj) * 17 + l15];
      *(f16x4*)(out + (size_t)tile * 512 + l * 8 + w2 * 4) = o;
    }
  } else {                 // W1 [32][32][32]: one block per head h
    int h = b - 2624;
    const float* in = W1 + h * 1024;
    int cc = t & 31, rr8 = t >> 5;
#pragma unroll
    for (int p = 0; p < 4; ++p) {
      int r = rr8 + p * 8;
      S[cc * 33 + r] = in[r * 32 + cc];
    }
    __syncthreads();
    if (t < 128) {
      int ntl = t >> 6, l = t & 63, q = l >> 4, l15 = l & 15;
      f16x8 o;
#pragma unroll
      for (int j = 0; j < 8; ++j)
        o[j] = (_Float16)S[(ntl * 16 + l15) * 33 + q * 8 + j];
      *(f16x8*)(V1p + (size_t)(h * 2 + ntl) * 512 + l * 8) = o;
    }
  }
}

// ---------------- K1: ripple layer 1 ----------------
// Output x1p fragment-major, kt-major: tile (kc, rt) at (kc*NRT + rt)*512.
// Grid 1-D, XCD-matched: all blocks of bm run on XCD bm&7 (matches k2 reader).
__global__ __launch_bounds__(256) void k1_ripple1(
    const float* __restrict__ state, const float* __restrict__ action,
    const _Float16* __restrict__ v1p, const float* __restrict__ b1,
    const float* __restrict__ g1, _Float16* __restrict__ x1p, int gro,
    int NRT, int xcdMatch) {
  __shared__ __align__(16) _Float16 SM[128 * 68];
  int g = blockIdx.x, bn, bm;
  if (xcdMatch) { int x = g & 7, r = g >> 3; bn = r & 7; bm = x + 8 * (r >> 3); }
  else { bn = g & 7; bm = g >> 3; }
  int t = threadIdx.x, w = t >> 6, l = t & 63, q = l >> 4, l15 = l & 15;
  int n0 = bn * 128, m0 = bm * 128;

  {  // stage sa tile [128][32] fp16, stride 40
    int r = t >> 1, half = t & 1;
    size_t grow = (size_t)(gro + m0 + r);
    float v[16];
    if (half == 0) {
      const float4* sp = (const float4*)(state + grow * 24);
      ((float4*)v)[0] = sp[0]; ((float4*)v)[1] = sp[1];
      ((float4*)v)[2] = sp[2]; ((float4*)v)[3] = sp[3];
    } else {
      const float4* sp = (const float4*)(state + grow * 24 + 16);
      ((float4*)v)[0] = sp[0]; ((float4*)v)[1] = sp[1];
      const float4* ap = (const float4*)(action + grow * 8);
      ((float4*)v)[2] = ap[0]; ((float4*)v)[3] = ap[1];
    }
    f16x8 h0, h1;
#pragma unroll
    for (int j = 0; j < 8; ++j) { h0[j] = (_Float16)v[j]; h1[j] = (_Float16)v[8 + j]; }
    *(f16x8*)&SM[r * 40 + half * 16] = h0;
    *(f16x8*)&SM[r * 40 + half * 16 + 8] = h1;
  }
  __syncthreads();

  int wr = w >> 1, wc = w & 1;
  f16x8 af[4], bf[4];
#pragma unroll
  for (int mi = 0; mi < 4; ++mi)
    af[mi] = *(const f16x8*)&SM[(wr * 64 + mi * 16 + l15) * 40 + q * 8];
#pragma unroll
  for (int ni = 0; ni < 4; ++ni)
    bf[ni] = *(const f16x8*)(v1p + (size_t)(bn * 8 + wc * 4 + ni) * 512 + l * 8);

  f32x4 acc[4][4] = {};
#pragma unroll
  for (int mi = 0; mi < 4; ++mi)
#pragma unroll
    for (int ni = 0; ni < 4; ++ni)
      acc[mi][ni] = __builtin_amdgcn_mfma_f32_16x16x32_f16(af[mi], bf[ni], acc[mi][ni], 0, 0, 0);

  // epilogue: 2 passes of 64 cols; pack (stride 68) -> fragment-major kt-major x1p
  for (int p = 0; p < 2; ++p) {
    __syncthreads();
    if (wc == p) {
#pragma unroll
      for (int ni = 0; ni < 4; ++ni) {
        int col = n0 + p * 64 + ni * 16 + l15;
        float sg = sigmoid_fast(g1[col >> 5]);
        float bias = b1[col];
#pragma unroll
        for (int mi = 0; mi < 4; ++mi)
#pragma unroll
          for (int r = 0; r < 4; ++r) {
            int rl = wr * 64 + mi * 16 + q * 4 + r;
            SM[rl * 68 + ni * 16 + l15] = (_Float16)(tanh_fast(acc[mi][ni][r] + bias) * sg);
          }
      }
    }
    __syncthreads();
#pragma unroll
    for (int i = 0; i < 4; ++i) {
      int c = t + i * 256;
      int kcL = c >> 9, rt = (c >> 6) & 7, ll = c & 63;
      int qq = ll >> 4, ll15 = ll & 15;
      int base = (rt * 16 + ll15) * 68 + kcL * 32 + qq * 8;
      union { f16x8 v; f16x4 h[2]; } u;
      u.h[0] = *(const f16x4*)&SM[base];
      u.h[1] = *(const f16x4*)&SM[base + 4];
      int kc = bn * 4 + p * 2 + kcL;
      *(f16x8*)(x1p + ((size_t)kc * NRT + (m0 >> 4) + rt) * 512 + ll * 8) = u.v;
    }
  }
}

// ---------------- K2: ripple layer 2 (the big GEMM) ----------------
// Barrier-free streaming, kt-major operands (immediate offsets), prefetch
// distance = 2 kt (loads issued after their consuming group, same registers).
// Reversed bm order per XCD to read k1's freshest dirty-L2 lines first.
__global__ __launch_bounds__(256, 2) void k2_ripple2(
    const _Float16* __restrict__ x1p, const _Float16* __restrict__ v2p,
    const float* __restrict__ b2, const float* __restrict__ g2,
    _Float16* __restrict__ x2p, int nbm, int NRT) {
  __shared__ __align__(16) _Float16 EP[4 * 64 * 36];
  int g = blockIdx.x;
  int bn, bm;
  if ((nbm & 7) == 0) {
    int x = g & 7, j = g >> 3, jj = j >> 2, nJ = nbm >> 3;
    bn = j & 3; bm = x + 8 * (nJ - 1 - jj);
  } else { bn = g & 3; bm = g >> 2; }
  int t = threadIdx.x, w = t >> 6, l = t & 63, q = l >> 4, l15 = l & 15;
  int wr = w >> 1, wc = w & 1;
  int rt0 = bm * 8 + wr * 4;
  int nt0 = bn * 16 + wc * 8;
  f32x4 acc[4][8] = {};

  const size_t aStep = (size_t)NRT * 512;
  const _Float16* aP = x1p + (size_t)rt0 * 512 + (size_t)l * 8;
  const _Float16* bP = v2p + (size_t)nt0 * 512 + (size_t)l * 8;

  f16x8 a0[4], a1[4], b0[8], b1[8];
#pragma unroll
  for (int mi = 0; mi < 4; ++mi) a0[mi] = *(const f16x8*)(aP + mi * 512);
#pragma unroll
  for (int ni = 0; ni < 8; ++ni) b0[ni] = *(const f16x8*)(bP + ni * 512);
#pragma unroll
  for (int mi = 0; mi < 4; ++mi) a1[mi] = *(const f16x8*)(aP + aStep + mi * 512);
#pragma unroll
  for (int ni = 0; ni < 8; ++ni) b1[ni] = *(const f16x8*)(bP + 32768 + ni * 512);
  aP += 2 * aStep; bP += 65536;

  for (int kt = 0; kt < 32; kt += 2) {
#pragma unroll
    for (int mi = 0; mi < 4; ++mi)
#pragma unroll
      for (int ni = 0; ni < 8; ++ni)
        acc[mi][ni] = __builtin_amdgcn_mfma_f32_16x16x32_f16(a0[mi], b0[ni], acc[mi][ni], 0, 0, 0);
    if (kt < 30) {   // load kt+2 into the just-consumed registers
#pragma unroll
      for (int mi = 0; mi < 4; ++mi) a0[mi] = *(const f16x8*)(aP + mi * 512);
#pragma unroll
      for (int ni = 0; ni < 8; ++ni) b0[ni] = *(const f16x8*)(bP + ni * 512);
    }
#pragma unroll
    for (int mi = 0; mi < 4; ++mi)
#pragma unroll
      for (int ni = 0; ni < 8; ++ni)
        acc[mi][ni] = __builtin_amdgcn_mfma_f32_16x16x32_f16(a1[mi], b1[ni], acc[mi][ni], 0, 0, 0);
    if (kt < 30) {   // load kt+3
#pragma unroll
      for (int mi = 0; mi < 4; ++mi) a1[mi] = *(const f16x8*)(aP + aStep + mi * 512);
#pragma unroll
      for (int ni = 0; ni < 8; ++ni) b1[ni] = *(const f16x8*)(bP + 32768 + ni * 512);
      aP += 2 * aStep; bP += 65536;
    }
  }

  // epilogue: per-wave LDS transform C/D -> fragment-major kt-major x2p
  _Float16* EPw = EP + w * (64 * 36);
  for (int kcg = 0; kcg < 4; ++kcg) {
#pragma unroll
    for (int np = 0; np < 2; ++np) {
      int ni = kcg * 2 + np;
      int col = (nt0 + ni) * 16 + l15;
      float sg = sigmoid_fast(g2[col >> 5]);
      float bias = b2[col];
#pragma unroll
      for (int mi = 0; mi < 4; ++mi)
#pragma unroll
        for (int r = 0; r < 4; ++r) {
          int row = mi * 16 + q * 4 + r;
          EPw[row * 36 + np * 16 + l15] = (_Float16)(tanh_fast(acc[mi][ni][r] + bias) * sg);
        }
    }
#pragma unroll
    for (int rt = 0; rt < 4; ++rt) {
      int base = (rt * 16 + l15) * 36 + q * 8;
      union { f16x8 v; f16x4 h[2]; } u;
      u.h[0] = *(const f16x4*)&EPw[base];
      u.h[1] = *(const f16x4*)&EPw[base + 4];
      int kc = (nt0 >> 1) + kcg;
      *(f16x8*)(x2p + ((size_t)kc * NRT + rt0 + rt) * 512 + l * 8) = u.v;
    }
  }
}

// ---------------- K3: fused q-network head ----------------
// GEMM3 streaming with kt-major x2p/T1p and distance-2 prefetch.
__global__ __launch_bounds__(512, 3) void k3_head(
    const _Float16* __restrict__ x2p, const _Float16* __restrict__ t1p,
    const _Float16* __restrict__ t2p,
    const float* __restrict__ bq1, const float* __restrict__ ln1g, const float* __restrict__ ln1b,
    const float* __restrict__ bq2, const float* __restrict__ ln2g, const float* __restrict__ ln2b,
    const float* __restrict__ wq3, const float* __restrict__ bq3,
    float* __restrict__ out, int NRT, int SROWS) {
  __shared__ __align__(16) _Float16 y1h[128 * 264];
  __shared__ float redA[128 * 4], redB[128 * 4];
  __shared__ float meanv[128], rstdv[128];
  int bm = blockIdx.x;
  int t = threadIdx.x, w = t >> 6, l = t & 63, q = l >> 4, l15 = l & 15;
  int wr = w >> 2, wc = w & 3;

  // slice decode (G<=2)
  int gt = bm * 8;
  int slice = 0;
  if (gt >= NRT) { slice = 1; gt -= NRT; }
  int rt0 = gt + wr * 4;

  // ---- GEMM3: [128 x 1024] @ [1024 x 256], streaming distance-2
  f32x4 acc[4][4] = {};
  const size_t aStep = (size_t)NRT * 512;
  const _Float16* aP = x2p + (size_t)slice * SROWS * 1024 + (size_t)rt0 * 512 + (size_t)l * 8;
  const _Float16* bP = t1p + (size_t)(wc * 4) * 512 + (size_t)l * 8;

  f16x8 a0[4], a1[4], b0[4], b1[4];
#pragma unroll
  for (int mi = 0; mi < 4; ++mi) a0[mi] = *(const f16x8*)(aP + mi * 512);
#pragma unroll
  for (int ni = 0; ni < 4; ++ni) b0[ni] = *(const f16x8*)(bP + ni * 512);
#pragma unroll
  for (int mi = 0; mi < 4; ++mi) a1[mi] = *(const f16x8*)(aP + aStep + mi * 512);
#pragma unroll
  for (int ni = 0; ni < 4; ++ni) b1[ni] = *(const f16x8*)(bP + 8192 + ni * 512);
  aP += 2 * aStep; bP += 16384;

  for (int kt = 0; kt < 32; kt += 2) {
#pragma unroll
    for (int mi = 0; mi < 4; ++mi)
#pragma unroll
      for (int ni = 0; ni < 4; ++ni)
        acc[mi][ni] = __builtin_amdgcn_mfma_f32_16x16x32_f16(a0[mi], b0[ni], acc[mi][ni], 0, 0, 0);
    if (kt < 30) {
#pragma unroll
      for (int mi = 0; mi < 4; ++mi) a0[mi] = *(const f16x8*)(aP + mi * 512);
#pragma unroll
      for (int ni = 0; ni < 4; ++ni) b0[ni] = *(const f16x8*)(bP + ni * 512);
    }
#pragma unroll
    for (int mi = 0; mi < 4; ++mi)
#pragma unroll
      for (int ni = 0; ni < 4; ++ni)
        acc[mi][ni] = __builtin_amdgcn_mfma_f32_16x16x32_f16(a1[mi], b1[ni], acc[mi][ni], 0, 0, 0);
    if (kt < 30) {
#pragma unroll
      for (int mi = 0; mi < 4; ++mi) a1[mi] = *(const f16x8*)(aP + aStep + mi * 512);
#pragma unroll
      for (int ni = 0; ni < 4; ++ni) b1[ni] = *(const f16x8*)(bP + 8192 + ni * 512);
      aP += 2 * aStep; bP += 16384;
    }
  }

  // bias + row-sum/sumsq over 256 cols
#pragma unroll
  for (int ni = 0; ni < 4; ++ni) {
    int col = wc * 64 + ni * 16 + l15;
    float b = bq1[col];
#pragma unroll
    for (int mi = 0; mi < 4; ++mi)
#pragma unroll
      for (int r = 0; r < 4; ++r) acc[mi][ni][r] += b;
  }
#pragma unroll
  for (int mi = 0; mi < 4; ++mi)
#pragma unroll
    for (int r = 0; r < 4; ++r) {
      int row = wr * 64 + mi * 16 + q * 4 + r;
      float s = 0.f, sq = 0.f;
#pragma unroll
      for (int ni = 0; ni < 4; ++ni) { float v = acc[mi][ni][r]; s += v; sq += v * v; }
#pragma unroll
      for (int off = 1; off < 16; off <<= 1) { s += __shfl_xor(s, off); sq += __shfl_xor(sq, off); }
      if (l15 == 0) { redA[row * 4 + wc] = s; redB[row * 4 + wc] = sq; }
    }
  __syncthreads();
  if (t < 128) {
    float s  = redA[t * 4] + redA[t * 4 + 1] + redA[t * 4 + 2] + redA[t * 4 + 3];
    float sq = redB[t * 4] + redB[t * 4 + 1] + redB[t * 4 + 2] + redB[t * 4 + 3];
    float mean = s * (1.0f / 256.0f);
    float var = sq * (1.0f / 256.0f) - mean * mean;
    meanv[t] = mean; rstdv[t] = rsqrtf(var + 1e-5f);
  }
  __syncthreads();
  // LN + relu -> y1h
#pragma unroll
  for (int mi = 0; mi < 4; ++mi)
#pragma unroll
    for (int ni = 0; ni < 4; ++ni)
#pragma unroll
      for (int r = 0; r < 4; ++r) {
        int row = wr * 64 + mi * 16 + q * 4 + r;
        int col = wc * 64 + ni * 16 + l15;
        float y = (acc[mi][ni][r] - meanv[row]) * rstdv[row] * ln1g[col] + ln1b[col];
        y = fmaxf(y, 0.f);
        y1h[row * 264 + col] = (_Float16)y;
      }
  __syncthreads();

  // ---- GEMM4: [128 x 256] @ [256 x 128]
  f32x4 a2[4][2] = {};
  for (int kt = 0; kt < 8; ++kt) {
    f16x8 af2[4];
#pragma unroll
    for (int mi = 0; mi < 4; ++mi)
      af2[mi] = *(const f16x8*)&y1h[(wr * 64 + mi * 16 + l15) * 264 + kt * 32 + q * 8];
#pragma unroll
    for (int ni = 0; ni < 2; ++ni) {
      f16x8 bf = *(const f16x8*)(t2p + (size_t)(wc * 2 + ni) * 4096 + kt * 512 + l * 8);
#pragma unroll
      for (int mi = 0; mi < 4; ++mi)
        a2[mi][ni] = __builtin_amdgcn_mfma_f32_16x16x32_f16(af2[mi], bf, a2[mi][ni], 0, 0, 0);
    }
  }
#pragma unroll
  for (int ni = 0; ni < 2; ++ni) {
    int col = wc * 32 + ni * 16 + l15;
    float b = bq2[col];
#pragma unroll
    for (int mi = 0; mi < 4; ++mi)
#pragma unroll
      for (int r = 0; r < 4; ++r) a2[mi][ni][r] += b;
  }
  __syncthreads();
#pragma unroll
  for (int mi = 0; mi < 4; ++mi)
#pragma unroll
    for (int r = 0; r < 4; ++r) {
      int row = wr * 64 + mi * 16 + q * 4 + r;
      float s = 0.f, sq = 0.f;
#pragma unroll
      for (int ni = 0; ni < 2; ++ni) { float v = a2[mi][ni][r]; s += v; sq += v * v; }
#pragma unroll
      for (int off = 1; off < 16; off <<= 1) { s += __shfl_xor(s, off); sq += __shfl_xor(sq, off); }
      if (l15 == 0) { redA[row * 4 + wc] = s; redB[row * 4 + wc] = sq; }
    }
  __syncthreads();
  if (t < 128) {
    float s  = redA[t * 4] + redA[t * 4 + 1] + redA[t * 4 + 2] + redA[t * 4 + 3];
    float sq = redB[t * 4] + redB[t * 4 + 1] + redB[t * 4 + 2] + redB[t * 4 + 3];
    float mean = s * (1.0f / 128.0f);
    float var = sq * (1.0f / 128.0f) - mean * mean;
    meanv[t] = mean; rstdv[t] = rsqrtf(var + 1e-5f);
  }
  __syncthreads();
  // LN + relu + dot(wq3)
#pragma unroll
  for (int mi = 0; mi < 4; ++mi)
#pragma unroll
    for (int r = 0; r < 4; ++r) {
      int row = wr * 64 + mi * 16 + q * 4 + r;
      float pr = 0.f;
#pragma unroll
      for (int ni = 0; ni < 2; ++ni) {
        int col = wc * 32 + ni * 16 + l15;
        float y = (a2[mi][ni][r] - meanv[row]) * rstdv[row] * ln2g[col] + ln2b[col];
        y = fmaxf(y, 0.f);
        pr += y * wq3[col];
      }
#pragma unroll
      for (int off = 1; off < 16; off <<= 1) pr += __shfl_xor(pr, off);
      if (l15 == 0) redA[row * 4 + wc] = pr;
    }
  __syncthreads();
  if (t < 128)
    out[bm * 128 + t] = redA[t * 4] + redA[t * 4 + 1] + redA[t * 4 + 2] + redA[t * 4 + 3] + bq3[0];
}

// ---------------- launcher ----------------
extern "C" void kernel_launch(void* const* d_in, const int* in_sizes, int n_in,
                              void* d_out, int out_size, void* d_ws, size_t ws_size,
                              hipStream_t stream) {
  const float* state  = (const float*)d_in[0];
  const float* action = (const float*)d_in[1];
  const float* W1  = (const float*)d_in[2];
  const float* b1  = (const float*)d_in[3];
  const float* g1  = (const float*)d_in[4];
  const float* W2  = (const float*)d_in[5];
  const float* b2  = (const float*)d_in[6];
  const float* g2  = (const float*)d_in[7];
  const float* Wq1 = (const float*)d_in[8];
  const float* bq1 = (const float*)d_in[9];
  const float* ln1g = (const float*)d_in[10];
  const float* ln1b = (const float*)d_in[11];
  const float* Wq2 = (const float*)d_in[12];
  const float* bq2 = (const float*)d_in[13];
  const float* ln2g = (const float*)d_in[14];
  const float* ln2b = (const float*)d_in[15];
  const float* Wq3 = (const float*)d_in[16];
  const float* bq3 = (const float*)d_in[17];
  int B = in_sizes[0] / 24;

  char* ws = (char*)d_ws;
  _Float16* V1p = (_Float16*)(ws);
  _Float16* V2p = (_Float16*)(ws + 65536);
  _Float16* T1p = (_Float16*)(ws + 65536 + 2097152);
  _Float16* T2p = (_Float16*)(ws + 65536 + 2097152 + 524288);
  size_t woff = (65536 + 2097152 + 524288 + 65536 + 4095) & ~(size_t)4095;

  size_t avail = ws_size > woff ? ws_size - woff : 0;
  int S, G;
  if (avail >= (size_t)32768 * 2048 * 3) {
    S = 32768; G = 2;
  } else {
    long rows = (long)(avail / 4096);
    if (rows > 32768) rows = 32768;
    rows &= ~127L;
    if (rows < 128) rows = 128;
    S = (int)rows; G = 1;
  }
  _Float16* x1 = (_Float16*)(ws + woff);
  _Float16* x2 = x1 + (size_t)S * 1024;
  int NRT = S / 16;

  prep_weights<<<2656, 256, 0, stream>>>(W1, W2, Wq1, Wq2, V1p, V2p, T1p, T2p);

  int nsl = (B + S - 1) / S;
  for (int i = 0; i < nsl; ++i) {
    int r0 = i * S;
    int Sc = S < (B - r0) ? S : (B - r0);
    int nbm = Sc / 128;
    int xm = (nbm & 7) == 0 ? 1 : 0;
    k1_ripple1<<<dim3(8 * nbm), 256, 0, stream>>>(state, action, V1p, b1, g1, x1, r0,
                                                  NRT, xm);
    k2_ripple2<<<dim3(4 * nbm), 256, 0, stream>>>(x1, V2p, b2, g2,
                                                  x2 + (size_t)(i % G) * S * 1024, nbm, NRT);
    if (i % G == G - 1 || i == nsl - 1) {
      int gstart = (i - i % G) * S;
      int nrows = r0 + Sc - gstart;
      k3_head<<<dim3(nrows / 128), 512, 0, stream>>>(x2, T1p, T2p, bq1, ln1g, ln1b,
                                                     bq2, ln2g, ln2b, Wq3, bq3,
                                                     (float*)d_out + gstart, NRT, S);
    }
  }
}

// Round 10
// 608.452 us; speedup vs baseline: 1.0464x; 1.0464x over previous
//
#include <hip/hip_runtime.h>
#include <hip/hip_bf16.h>

typedef _Float16 f16x8 __attribute__((ext_vector_type(8)));
typedef _Float16 f16x4 __attribute__((ext_vector_type(4)));
typedef float f32x4 __attribute__((ext_vector_type(4)));

__device__ __forceinline__ float tanh_fast(float x) {
  float e = __expf(2.0f * x);
  return 1.0f - 2.0f * __builtin_amdgcn_rcpf(e + 1.0f);
}
__device__ __forceinline__ float sigmoid_fast(float x) {
  return __builtin_amdgcn_rcpf(1.0f + __expf(-x));
}

// ---------------- K0: weight prep ----------------
// Fragment-major tiles of 512 halfwords: lane l elem j = B[k=kt*32+(l>>4)*8+j][col=nt*16+(l&15)].
// V1p: tile = nt (32 k only). V2p: tile = kt*64 + nt (kt-major). T1p: tile = kt*16 + nt.
// T2p: tile = nt*8 + kt.
__global__ __launch_bounds__(256) void prep_weights(
    const float* __restrict__ W1, const float* __restrict__ W2,
    const float* __restrict__ Wq1, const float* __restrict__ Wq2,
    _Float16* __restrict__ V1p, _Float16* __restrict__ V2p,
    _Float16* __restrict__ T1p, _Float16* __restrict__ T2p) {
  __shared__ float S[32 * 33];
  int b = blockIdx.x, t = threadIdx.x;
  if (b < 2624) {
    const float* in; _Float16* out; int N, nc0, tile;
    if (b < 2048) {        // W2 [32][1024][32]: h, ntl, kt
      int h = b >> 6, rem = b & 63, ntl = rem >> 5, kt = rem & 31;
      in = W2 + (size_t)h * 32768 + (size_t)kt * 32 * 32;
      N = 32; nc0 = ntl * 16;
      out = V2p; tile = kt * 64 + (h * 2 + ntl);
    } else if (b < 2560) { // Wq1 [1024][256]
      int i = b - 2048, nt = i >> 5, kt = i & 31;
      in = Wq1 + (size_t)kt * 32 * 256; N = 256; nc0 = nt * 16;
      out = T1p; tile = kt * 16 + nt;
    } else {               // Wq2 [256][128]
      int i = b - 2560, nt = i >> 3, kt = i & 7;
      in = Wq2 + (size_t)kt * 32 * 128; N = 128; nc0 = nt * 16;
      out = T2p; tile = nt * 8 + kt;
    }
    if (t < 128) {
      int r = t >> 2, c4 = (t & 3) * 4;
      const float4 v = *(const float4*)(in + (size_t)r * N + nc0 + c4);
      S[r * 17 + c4 + 0] = v.x; S[r * 17 + c4 + 1] = v.y;
      S[r * 17 + c4 + 2] = v.z; S[r * 17 + c4 + 3] = v.w;
    }
    __syncthreads();
    if (t < 128) {
      int w2 = t >> 6, l = t & 63, q = l >> 4, l15 = l & 15;
      f16x4 o;
#pragma unroll
      for (int jj = 0; jj < 4; ++jj)
        o[jj] = (_Float16)S[(q * 8 + w2 * 4 + jj) * 17 + l15];
      *(f16x4*)(out + (size_t)tile * 512 + l * 8 + w2 * 4) = o;
    }
  } else {                 // W1 [32][32][32]: one block per head h
    int h = b - 2624;
    const float* in = W1 + h * 1024;
    int cc = t & 31, rr8 = t >> 5;
#pragma unroll
    for (int p = 0; p < 4; ++p) {
      int r = rr8 + p * 8;
      S[cc * 33 + r] = in[r * 32 + cc];
    }
    __syncthreads();
    if (t < 128) {
      int ntl = t >> 6, l = t & 63, q = l >> 4, l15 = l & 15;
      f16x8 o;
#pragma unroll
      for (int j = 0; j < 8; ++j)
        o[j] = (_Float16)S[(ntl * 16 + l15) * 33 + q * 8 + j];
      *(f16x8*)(V1p + (size_t)(h * 2 + ntl) * 512 + l * 8) = o;
    }
  }
}

// ---------------- K12: fused ripple1 + ripple2 ----------------
// Block = 128 rows x 512 cols, 512 threads (8 waves). Per K-chunk kc (128 k):
//   R: recompute x1 chunk via MFMA(sa, V1p) + tanh -> LDS frag dbuf (1 barrier)
//   G: main GEMM, A from LDS (ds_read_b128), B from L2-hot V2p (ping-pong).
// No HBM-latency operand in the K-loop; x1 never touches global memory.
// XF: each buffer holds 32 tiles (4 k-tiles x 8 row-tiles) x 512 hw = 16384 hw.
__global__ __launch_bounds__(512, 2) void k12_fused(
    const float* __restrict__ state, const float* __restrict__ action,
    const _Float16* __restrict__ v1p, const float* __restrict__ b1,
    const float* __restrict__ g1,
    const _Float16* __restrict__ v2p, const float* __restrict__ b2,
    const float* __restrict__ g2,
    _Float16* __restrict__ x2p, int gro, int NRT) {
  __shared__ __align__(16) _Float16 SA[128 * 40];        // 10 KB
  __shared__ __align__(16) _Float16 XF[2 * 16384];       // 64 KB frag dbuf
  __shared__ __align__(16) _Float16 EP[8 * 64 * 36];     // 36 KB wave-private
  int g = blockIdx.x;
  int bn = g & 1, bm = g >> 1;
  int t = threadIdx.x, w = t >> 6, l = t & 63, q = l >> 4, l15 = l & 15;
  int wrow = w & 1;          // row half (R and G phases)
  int cg = w >> 1;           // R: 32-col group; G: 128-col group
  int m0 = bm * 128;

  {  // stage sa tile [128][32] fp16, stride 40; 4 threads/row
    int r = t >> 2, q4 = t & 3;
    size_t grow = (size_t)(gro + m0 + r);
    float v[8];
    if (q4 < 3) {
      const float4* sp = (const float4*)(state + grow * 24 + q4 * 8);
      ((float4*)v)[0] = sp[0]; ((float4*)v)[1] = sp[1];
    } else {
      const float4* ap = (const float4*)(action + grow * 8);
      ((float4*)v)[0] = ap[0]; ((float4*)v)[1] = ap[1];
    }
    f16x8 h0;
#pragma unroll
    for (int j = 0; j < 8; ++j) h0[j] = (_Float16)v[j];
    *(f16x8*)&SA[r * 40 + q4 * 8] = h0;
  }
  __syncthreads();

  f32x4 acc[4][8] = {};
  _Float16* EPw = EP + w * (64 * 36);

  // V1p prefetch for kc=0
  f16x8 rb[2];
#pragma unroll
  for (int ni = 0; ni < 2; ++ni)
    rb[ni] = *(const f16x8*)(v1p + (size_t)(cg * 2 + ni) * 512 + l * 8);

  const int nt0 = bn * 32 + cg * 8;    // G-phase B tile base
  const _Float16* bBase = v2p + (size_t)nt0 * 512 + (size_t)l * 8;

  for (int kc = 0; kc < 8; ++kc) {
    // ---- R phase: x1 chunk cols kc*128 + cg*32 .. +31, rows wrow*64..+63
    f16x8 asa[4];
#pragma unroll
    for (int mi = 0; mi < 4; ++mi)
      asa[mi] = *(const f16x8*)&SA[(wrow * 64 + mi * 16 + l15) * 40 + q * 8];
    f32x4 a1[4][2] = {};
#pragma unroll
    for (int mi = 0; mi < 4; ++mi)
#pragma unroll
      for (int ni = 0; ni < 2; ++ni)
        a1[mi][ni] = __builtin_amdgcn_mfma_f32_16x16x32_f16(asa[mi], rb[ni], a1[mi][ni], 0, 0, 0);
    // tanh+gate -> EPw (C layout, stride 36)
#pragma unroll
    for (int ni = 0; ni < 2; ++ni) {
      int col = kc * 128 + cg * 32 + ni * 16 + l15;
      float sg = sigmoid_fast(g1[col >> 5]);
      float bias = b1[col];
#pragma unroll
      for (int mi = 0; mi < 4; ++mi)
#pragma unroll
        for (int r = 0; r < 4; ++r)
          EPw[(mi * 16 + q * 4 + r) * 36 + ni * 16 + l15] =
              (_Float16)(tanh_fast(a1[mi][ni][r] + bias) * sg);
    }
    // repack -> x1frag[buf]: tile (ktL=cg, rt=wrow*4+rtl)
    _Float16* buf = XF + (kc & 1) * 16384;
#pragma unroll
    for (int rtl = 0; rtl < 4; ++rtl) {
      int base = (rtl * 16 + l15) * 36 + q * 8;
      union { f16x8 v; f16x4 h[2]; } u;
      u.h[0] = *(const f16x4*)&EPw[base];
      u.h[1] = *(const f16x4*)&EPw[base + 4];
      *(f16x8*)(buf + ((cg * 8 + wrow * 4 + rtl) * 64 + l) * 8) = u.v;
    }
    __syncthreads();

    // ---- G phase: 4 kt over this chunk; A from LDS, B ping-pong from V2p
    if (kc < 7) {   // prefetch V1p for next R phase
#pragma unroll
      for (int ni = 0; ni < 2; ++ni)
        rb[ni] = *(const f16x8*)(v1p + (size_t)((kc + 1) * 8 + cg * 2 + ni) * 512 + l * 8);
    }
    int ktg = kc * 4;
    f16x8 bb0[8], bb1[8];
#pragma unroll
    for (int ni = 0; ni < 8; ++ni)
      bb0[ni] = *(const f16x8*)(bBase + (size_t)(ktg * 64 + ni) * 512);
#pragma unroll
    for (int ni = 0; ni < 8; ++ni)
      bb1[ni] = *(const f16x8*)(bBase + (size_t)((ktg + 1) * 64 + ni) * 512);
#pragma unroll
    for (int ktL = 0; ktL < 4; ++ktL) {
      f16x8 af[4];
#pragma unroll
      for (int mi = 0; mi < 4; ++mi)
        af[mi] = *(const f16x8*)(buf + ((ktL * 8 + wrow * 4 + mi) * 64 + l) * 8);
      f16x8* bb = (ktL & 1) ? bb1 : bb0;
#pragma unroll
      for (int mi = 0; mi < 4; ++mi)
#pragma unroll
        for (int ni = 0; ni < 8; ++ni)
          acc[mi][ni] = __builtin_amdgcn_mfma_f32_16x16x32_f16(af[mi], bb[ni], acc[mi][ni], 0, 0, 0);
      if (ktL == 0) {
#pragma unroll
        for (int ni = 0; ni < 8; ++ni)
          bb0[ni] = *(const f16x8*)(bBase + (size_t)((ktg + 2) * 64 + ni) * 512);
      } else if (ktL == 1) {
#pragma unroll
        for (int ni = 0; ni < 8; ++ni)
          bb1[ni] = *(const f16x8*)(bBase + (size_t)((ktg + 3) * 64 + ni) * 512);
      }
    }
  }

  // ---- epilogue: gate+tanh on acc -> fragment-major x2p (wave-private EPw)
  for (int kcg = 0; kcg < 4; ++kcg) {
#pragma unroll
    for (int np = 0; np < 2; ++np) {
      int ni = kcg * 2 + np;
      int col = (nt0 + ni) * 16 + l15;
      float sg = sigmoid_fast(g2[col >> 5]);
      float bias = b2[col];
#pragma unroll
      for (int mi = 0; mi < 4; ++mi)
#pragma unroll
        for (int r = 0; r < 4; ++r)
          EPw[(mi * 16 + q * 4 + r) * 36 + np * 16 + l15] =
              (_Float16)(tanh_fast(acc[mi][ni][r] + bias) * sg);
    }
#pragma unroll
    for (int rtl = 0; rtl < 4; ++rtl) {
      int base = (rtl * 16 + l15) * 36 + q * 8;
      union { f16x8 v; f16x4 h[2]; } u;
      u.h[0] = *(const f16x4*)&EPw[base];
      u.h[1] = *(const f16x4*)&EPw[base + 4];
      int kc2 = (nt0 >> 1) + kcg;
      int rt = bm * 8 + wrow * 4 + rtl;
      *(f16x8*)(x2p + ((size_t)kc2 * NRT + rt) * 512 + l * 8) = u.v;
    }
  }
}

// ---------------- K3: fused q-network head ----------------
__global__ __launch_bounds__(512, 3) void k3_head(
    const _Float16* __restrict__ x2p, const _Float16* __restrict__ t1p,
    const _Float16* __restrict__ t2p,
    const float* __restrict__ bq1, const float* __restrict__ ln1g, const float* __restrict__ ln1b,
    const float* __restrict__ bq2, const float* __restrict__ ln2g, const float* __restrict__ ln2b,
    const float* __restrict__ wq3, const float* __restrict__ bq3,
    float* __restrict__ out, int NRT, int SROWS) {
  __shared__ __align__(16) _Float16 y1h[128 * 264];
  __shared__ float redA[128 * 4], redB[128 * 4];
  __shared__ float meanv[128], rstdv[128];
  int bm = blockIdx.x;
  int t = threadIdx.x, w = t >> 6, l = t & 63, q = l >> 4, l15 = l & 15;
  int wr = w >> 2, wc = w & 3;

  int gt = bm * 8;
  int slice = 0;
  if (gt >= NRT) { slice = 1; gt -= NRT; }
  int rt0 = gt + wr * 4;

  f32x4 acc[4][4] = {};
  const size_t aStep = (size_t)NRT * 512;
  const _Float16* aP = x2p + (size_t)slice * SROWS * 1024 + (size_t)rt0 * 512 + (size_t)l * 8;
  const _Float16* bP = t1p + (size_t)(wc * 4) * 512 + (size_t)l * 8;

  f16x8 a0[4], a1[4], b0[4], b1[4];
#pragma unroll
  for (int mi = 0; mi < 4; ++mi) a0[mi] = *(const f16x8*)(aP + mi * 512);
#pragma unroll
  for (int ni = 0; ni < 4; ++ni) b0[ni] = *(const f16x8*)(bP + ni * 512);
#pragma unroll
  for (int mi = 0; mi < 4; ++mi) a1[mi] = *(const f16x8*)(aP + aStep + mi * 512);
#pragma unroll
  for (int ni = 0; ni < 4; ++ni) b1[ni] = *(const f16x8*)(bP + 8192 + ni * 512);
  aP += 2 * aStep; bP += 16384;

  for (int kt = 0; kt < 32; kt += 2) {
#pragma unroll
    for (int mi = 0; mi < 4; ++mi)
#pragma unroll
      for (int ni = 0; ni < 4; ++ni)
        acc[mi][ni] = __builtin_amdgcn_mfma_f32_16x16x32_f16(a0[mi], b0[ni], acc[mi][ni], 0, 0, 0);
    if (kt < 30) {
#pragma unroll
      for (int mi = 0; mi < 4; ++mi) a0[mi] = *(const f16x8*)(aP + mi * 512);
#pragma unroll
      for (int ni = 0; ni < 4; ++ni) b0[ni] = *(const f16x8*)(bP + ni * 512);
    }
#pragma unroll
    for (int mi = 0; mi < 4; ++mi)
#pragma unroll
      for (int ni = 0; ni < 4; ++ni)
        acc[mi][ni] = __builtin_amdgcn_mfma_f32_16x16x32_f16(a1[mi], b1[ni], acc[mi][ni], 0, 0, 0);
    if (kt < 30) {
#pragma unroll
      for (int mi = 0; mi < 4; ++mi) a1[mi] = *(const f16x8*)(aP + aStep + mi * 512);
#pragma unroll
      for (int ni = 0; ni < 4; ++ni) b1[ni] = *(const f16x8*)(bP + 8192 + ni * 512);
      aP += 2 * aStep; bP += 16384;
    }
  }

#pragma unroll
  for (int ni = 0; ni < 4; ++ni) {
    int col = wc * 64 + ni * 16 + l15;
    float b = bq1[col];
#pragma unroll
    for (int mi = 0; mi < 4; ++mi)
#pragma unroll
      for (int r = 0; r < 4; ++r) acc[mi][ni][r] += b;
  }
#pragma unroll
  for (int mi = 0; mi < 4; ++mi)
#pragma unroll
    for (int r = 0; r < 4; ++r) {
      int row = wr * 64 + mi * 16 + q * 4 + r;
      float s = 0.f, sq = 0.f;
#pragma unroll
      for (int ni = 0; ni < 4; ++ni) { float v = acc[mi][ni][r]; s += v; sq += v * v; }
#pragma unroll
      for (int off = 1; off < 16; off <<= 1) { s += __shfl_xor(s, off); sq += __shfl_xor(sq, off); }
      if (l15 == 0) { redA[row * 4 + wc] = s; redB[row * 4 + wc] = sq; }
    }
  __syncthreads();
  if (t < 128) {
    float s  = redA[t * 4] + redA[t * 4 + 1] + redA[t * 4 + 2] + redA[t * 4 + 3];
    float sq = redB[t * 4] + redB[t * 4 + 1] + redB[t * 4 + 2] + redB[t * 4 + 3];
    float mean = s * (1.0f / 256.0f);
    float var = sq * (1.0f / 256.0f) - mean * mean;
    meanv[t] = mean; rstdv[t] = rsqrtf(var + 1e-5f);
  }
  __syncthreads();
#pragma unroll
  for (int mi = 0; mi < 4; ++mi)
#pragma unroll
    for (int ni = 0; ni < 4; ++ni)
#pragma unroll
      for (int r = 0; r < 4; ++r) {
        int row = wr * 64 + mi * 16 + q * 4 + r;
        int col = wc * 64 + ni * 16 + l15;
        float y = (acc[mi][ni][r] - meanv[row]) * rstdv[row] * ln1g[col] + ln1b[col];
        y = fmaxf(y, 0.f);
        y1h[row * 264 + col] = (_Float16)y;
      }
  __syncthreads();

  f32x4 a2[4][2] = {};
  for (int kt = 0; kt < 8; ++kt) {
    f16x8 af2[4];
#pragma unroll
    for (int mi = 0; mi < 4; ++mi)
      af2[mi] = *(const f16x8*)&y1h[(wr * 64 + mi * 16 + l15) * 264 + kt * 32 + q * 8];
#pragma unroll
    for (int ni = 0; ni < 2; ++ni) {
      f16x8 bf = *(const f16x8*)(t2p + (size_t)(wc * 2 + ni) * 4096 + kt * 512 + l * 8);
#pragma unroll
      for (int mi = 0; mi < 4; ++mi)
        a2[mi][ni] = __builtin_amdgcn_mfma_f32_16x16x32_f16(af2[mi], bf, a2[mi][ni], 0, 0, 0);
    }
  }
#pragma unroll
  for (int ni = 0; ni < 2; ++ni) {
    int col = wc * 32 + ni * 16 + l15;
    float b = bq2[col];
#pragma unroll
    for (int mi = 0; mi < 4; ++mi)
#pragma unroll
      for (int r = 0; r < 4; ++r) a2[mi][ni][r] += b;
  }
  __syncthreads();
#pragma unroll
  for (int mi = 0; mi < 4; ++mi)
#pragma unroll
    for (int r = 0; r < 4; ++r) {
      int row = wr * 64 + mi * 16 + q * 4 + r;
      float s = 0.f, sq = 0.f;
#pragma unroll
      for (int ni = 0; ni < 2; ++ni) { float v = a2[mi][ni][r]; s += v; sq += v * v; }
#pragma unroll
      for (int off = 1; off < 16; off <<= 1) { s += __shfl_xor(s, off); sq += __shfl_xor(sq, off); }
      if (l15 == 0) { redA[row * 4 + wc] = s; redB[row * 4 + wc] = sq; }
    }
  __syncthreads();
  if (t < 128) {
    float s  = redA[t * 4] + redA[t * 4 + 1] + redA[t * 4 + 2] + redA[t * 4 + 3];
    float sq = redB[t * 4] + redB[t * 4 + 1] + redB[t * 4 + 2] + redB[t * 4 + 3];
    float mean = s * (1.0f / 128.0f);
    float var = sq * (1.0f / 128.0f) - mean * mean;
    meanv[t] = mean; rstdv[t] = rsqrtf(var + 1e-5f);
  }
  __syncthreads();
#pragma unroll
  for (int mi = 0; mi < 4; ++mi)
#pragma unroll
    for (int r = 0; r < 4; ++r) {
      int row = wr * 64 + mi * 16 + q * 4 + r;
      float pr = 0.f;
#pragma unroll
      for (int ni = 0; ni < 2; ++ni) {
        int col = wc * 32 + ni * 16 + l15;
        float y = (a2[mi][ni][r] - meanv[row]) * rstdv[row] * ln2g[col] + ln2b[col];
        y = fmaxf(y, 0.f);
        pr += y * wq3[col];
      }
#pragma unroll
      for (int off = 1; off < 16; off <<= 1) pr += __shfl_xor(pr, off);
      if (l15 == 0) redA[row * 4 + wc] = pr;
    }
  __syncthreads();
  if (t < 128)
    out[bm * 128 + t] = redA[t * 4] + redA[t * 4 + 1] + redA[t * 4 + 2] + redA[t * 4 + 3] + bq3[0];
}

// ---------------- launcher ----------------
extern "C" void kernel_launch(void* const* d_in, const int* in_sizes, int n_in,
                              void* d_out, int out_size, void* d_ws, size_t ws_size,
                              hipStream_t stream) {
  const float* state  = (const float*)d_in[0];
  const float* action = (const float*)d_in[1];
  const float* W1  = (const float*)d_in[2];
  const float* b1  = (const float*)d_in[3];
  const float* g1  = (const float*)d_in[4];
  const float* W2  = (const float*)d_in[5];
  const float* b2  = (const float*)d_in[6];
  const float* g2  = (const float*)d_in[7];
  const float* Wq1 = (const float*)d_in[8];
  const float* bq1 = (const float*)d_in[9];
  const float* ln1g = (const float*)d_in[10];
  const float* ln1b = (const float*)d_in[11];
  const float* Wq2 = (const float*)d_in[12];
  const float* bq2 = (const float*)d_in[13];
  const float* ln2g = (const float*)d_in[14];
  const float* ln2b = (const float*)d_in[15];
  const float* Wq3 = (const float*)d_in[16];
  const float* bq3 = (const float*)d_in[17];
  int B = in_sizes[0] / 24;

  char* ws = (char*)d_ws;
  _Float16* V1p = (_Float16*)(ws);
  _Float16* V2p = (_Float16*)(ws + 65536);
  _Float16* T1p = (_Float16*)(ws + 65536 + 2097152);
  _Float16* T2p = (_Float16*)(ws + 65536 + 2097152 + 524288);
  size_t woff = (65536 + 2097152 + 524288 + 65536 + 4095) & ~(size_t)4095;

  size_t avail = ws_size > woff ? ws_size - woff : 0;
  int S, G;
  if (avail >= (size_t)32768 * 2048 * 2) {      // x2 only: 2 slices of S rows
    S = 32768; G = 2;
  } else {
    long rows = (long)(avail / 2048);           // x2 fp16 1024-wide, single slice
    if (rows > 32768) rows = 32768;
    rows &= ~127L;
    if (rows < 128) rows = 128;
    S = (int)rows; G = 1;
  }
  _Float16* x2 = (_Float16*)(ws + woff);
  int NRT = S / 16;

  prep_weights<<<2656, 256, 0, stream>>>(W1, W2, Wq1, Wq2, V1p, V2p, T1p, T2p);

  int nsl = (B + S - 1) / S;
  for (int i = 0; i < nsl; ++i) {
    int r0 = i * S;
    int Sc = S < (B - r0) ? S : (B - r0);
    int nbm = Sc / 128;
    k12_fused<<<dim3(2 * nbm), 512, 0, stream>>>(state, action, V1p, b1, g1,
                                                 V2p, b2, g2,
                                                 x2 + (size_t)(i % G) * S * 1024, r0, NRT);
    if (i % G == G - 1 || i == nsl - 1) {
      int gstart = (i - i % G) * S;
      int nrows = r0 + Sc - gstart;
      k3_head<<<dim3(nrows / 128), 512, 0, stream>>>(x2, T1p, T2p, bq1, ln1g, ln1b,
                                                     bq2, ln2g, ln2b, Wq3, bq3,
                                                     (float*)d_out + gstart, NRT, S);
    }
  }
}

// Round 11
// 605.391 us; speedup vs baseline: 1.0517x; 1.0051x over previous
//
#include <hip/hip_runtime.h>
#include <hip/hip_bf16.h>

typedef _Float16 f16x8 __attribute__((ext_vector_type(8)));
typedef _Float16 f16x4 __attribute__((ext_vector_type(4)));
typedef float f32x4 __attribute__((ext_vector_type(4)));

__device__ __forceinline__ float tanh_fast(float x) {
  float e = __expf(2.0f * x);
  return 1.0f - 2.0f * __builtin_amdgcn_rcpf(e + 1.0f);
}
__device__ __forceinline__ float sigmoid_fast(float x) {
  return __builtin_amdgcn_rcpf(1.0f + __expf(-x));
}

// ---------------- K0: weight prep ----------------
// Fragment tiles of 512 hw. PI k-order (W2, Wq1): lane l elem j holds
// B[k = kt*32 + pi(q,j)][col = nt*16 + l15], pi(q,j) = q*4 + (j&3) + 16*(j>>2).
// Plain k-order (Wq2): k = q*8 + j.  V1p: plain (it is the R-phase A operand).
// V2p tile = kt*64 + nt; T1p tile = kt*16 + nt; T2p tile = nt*8 + kt.
__global__ __launch_bounds__(256) void prep_weights(
    const float* __restrict__ W1, const float* __restrict__ W2,
    const float* __restrict__ Wq1, const float* __restrict__ Wq2,
    _Float16* __restrict__ V1p, _Float16* __restrict__ V2p,
    _Float16* __restrict__ T1p, _Float16* __restrict__ T2p) {
  __shared__ float S[32 * 33];
  int b = blockIdx.x, t = threadIdx.x;
  if (b < 2624) {
    const float* in; _Float16* out; int N, nc0, tile, use_pi;
    if (b < 2048) {        // W2 [32][1024][32]: h, ntl, kt  (PI)
      int h = b >> 6, rem = b & 63, ntl = rem >> 5, kt = rem & 31;
      in = W2 + (size_t)h * 32768 + (size_t)kt * 32 * 32;
      N = 32; nc0 = ntl * 16;
      out = V2p; tile = kt * 64 + (h * 2 + ntl); use_pi = 1;
    } else if (b < 2560) { // Wq1 [1024][256]  (PI)
      int i = b - 2048, nt = i >> 5, kt = i & 31;
      in = Wq1 + (size_t)kt * 32 * 256; N = 256; nc0 = nt * 16;
      out = T1p; tile = kt * 16 + nt; use_pi = 1;
    } else {               // Wq2 [256][128]  (plain)
      int i = b - 2560, nt = i >> 3, kt = i & 7;
      in = Wq2 + (size_t)kt * 32 * 128; N = 128; nc0 = nt * 16;
      out = T2p; tile = nt * 8 + kt; use_pi = 0;
    }
    if (t < 128) {
      int r = t >> 2, c4 = (t & 3) * 4;
      const float4 v = *(const float4*)(in + (size_t)r * N + nc0 + c4);
      S[r * 17 + c4 + 0] = v.x; S[r * 17 + c4 + 1] = v.y;
      S[r * 17 + c4 + 2] = v.z; S[r * 17 + c4 + 3] = v.w;
    }
    __syncthreads();
    if (t < 128) {
      int w2 = t >> 6, l = t & 63, q = l >> 4, l15 = l & 15;
      f16x4 o;
#pragma unroll
      for (int jj = 0; jj < 4; ++jj) {
        int kl = use_pi ? (q * 4 + jj + w2 * 16) : (q * 8 + w2 * 4 + jj);
        o[jj] = (_Float16)S[kl * 17 + l15];
      }
      *(f16x4*)(out + (size_t)tile * 512 + l * 8 + w2 * 4) = o;
    }
  } else {                 // W1 [32][32][32]: one block per head h (plain)
    int h = b - 2624;
    const float* in = W1 + h * 1024;
    int cc = t & 31, rr8 = t >> 5;
#pragma unroll
    for (int p = 0; p < 4; ++p) {
      int r = rr8 + p * 8;
      S[cc * 33 + r] = in[r * 32 + cc];
    }
    __syncthreads();
    if (t < 128) {
      int ntl = t >> 6, l = t & 63, q = l >> 4, l15 = l & 15;
      f16x8 o;
#pragma unroll
      for (int j = 0; j < 8; ++j)
        o[j] = (_Float16)S[(ntl * 16 + l15) * 33 + q * 8 + j];
      *(f16x8*)(V1p + (size_t)(h * 2 + ntl) * 512 + l * 8) = o;
    }
  }
}

// ---------------- K12: fused ripple1 + ripple2, pi-identity repack ----------------
// R phase computed operand-swapped: D = mfma(V1p_frag, sa_frag) gives lane l:
// m=l15, c=q*4+r -> post-tanh f16x8 IS the G-phase x1-fragment under pi.
// G phase swapped: D = mfma(V2p_pi_frag, x1_frag) -> lane l: n=q*4+r, m=l15 ->
// post-tanh f16x8 IS k3's A-fragment -> direct global store, no epilogue LDS.
__global__ __launch_bounds__(512, 2) void k12_fused(
    const float* __restrict__ state, const float* __restrict__ action,
    const _Float16* __restrict__ v1p, const float* __restrict__ b1,
    const float* __restrict__ g1,
    const _Float16* __restrict__ v2p, const float* __restrict__ b2,
    const float* __restrict__ g2,
    _Float16* __restrict__ x2p, int gro, int NRT) {
  __shared__ __align__(16) _Float16 SA[128 * 40];        // 10 KB
  __shared__ __align__(16) _Float16 XF[2 * 16384];       // 64 KB frag dbuf
  int g = blockIdx.x;
  int bn = g & 1, bm = g >> 1;
  int t = threadIdx.x, w = t >> 6, l = t & 63, q = l >> 4, l15 = l & 15;
  int wrow = w & 1;          // m-half (rows 0-63 / 64-127)
  int cg = w >> 1;           // R: ktL owner; G: 128-col group
  int m0 = bm * 128;

  {  // stage sa tile [128][32] fp16, stride 40; 4 threads/row
    int r = t >> 2, q4 = t & 3;
    size_t grow = (size_t)(gro + m0 + r);
    float v[8];
    if (q4 < 3) {
      const float4* sp = (const float4*)(state + grow * 24 + q4 * 8);
      ((float4*)v)[0] = sp[0]; ((float4*)v)[1] = sp[1];
    } else {
      const float4* ap = (const float4*)(action + grow * 8);
      ((float4*)v)[0] = ap[0]; ((float4*)v)[1] = ap[1];
    }
    f16x8 h0;
#pragma unroll
    for (int j = 0; j < 8; ++j) h0[j] = (_Float16)v[j];
    *(f16x8*)&SA[r * 40 + q4 * 8] = h0;
  }
  __syncthreads();

  // loop-invariant sa fragments (B operand of R phase): sa[mtile*16+l15][q*8+j]
  f16x8 asa[4];
#pragma unroll
  for (int p = 0; p < 4; ++p)
    asa[p] = *(const f16x8*)&SA[((wrow * 4 + p) * 16 + l15) * 40 + q * 8];

  // V1p fragments for kc=0 (A operand): W1[d=q*8+j][c = (cg*2+ni)*16+l15]
  f16x8 rb[2];
#pragma unroll
  for (int ni = 0; ni < 2; ++ni)
    rb[ni] = *(const f16x8*)(v1p + (size_t)(cg * 2 + ni) * 512 + l * 8);

  const int nt0 = bn * 32 + cg * 8;
  const _Float16* bBase = v2p + (size_t)nt0 * 512 + (size_t)l * 8;
  f32x4 acc[4][8] = {};

  for (int kc = 0; kc < 8; ++kc) {
    int ktg = kc * 4;
    // issue G-phase kt 0/1 B loads early — they complete during R compute
    f16x8 bb0[8], bb1[8];
#pragma unroll
    for (int ni = 0; ni < 8; ++ni)
      bb0[ni] = *(const f16x8*)(bBase + (size_t)(ktg * 64 + ni) * 512);
#pragma unroll
    for (int ni = 0; ni < 8; ++ni)
      bb1[ni] = *(const f16x8*)(bBase + (size_t)((ktg + 1) * 64 + ni) * 512);

    // ---- R phase: this wave produces x1-frags (mtile=wrow*4+p, ktL=cg)
    _Float16* buf = XF + (kc & 1) * 16384;
    float sg1 = sigmoid_fast(g1[kc * 4 + cg]);
    f32x4 bs0 = *(const f32x4*)(b1 + kc * 128 + cg * 32 + q * 4);
    f32x4 bs1 = *(const f32x4*)(b1 + kc * 128 + cg * 32 + 16 + q * 4);
#pragma unroll
    for (int p = 0; p < 4; ++p) {
      f32x4 d0 = {}, d1 = {};
      d0 = __builtin_amdgcn_mfma_f32_16x16x32_f16(rb[0], asa[p], d0, 0, 0, 0);
      d1 = __builtin_amdgcn_mfma_f32_16x16x32_f16(rb[1], asa[p], d1, 0, 0, 0);
      f16x8 o;
#pragma unroll
      for (int r = 0; r < 4; ++r) {
        o[r]     = (_Float16)(tanh_fast(d0[r] + bs0[r]) * sg1);
        o[4 + r] = (_Float16)(tanh_fast(d1[r] + bs1[r]) * sg1);
      }
      *(f16x8*)(buf + (size_t)(cg * 8 + wrow * 4 + p) * 512 + l * 8) = o;
    }
    __syncthreads();
    if (kc < 7) {   // V1p prefetch for next R
#pragma unroll
      for (int ni = 0; ni < 2; ++ni)
        rb[ni] = *(const f16x8*)(v1p + (size_t)((kc + 1) * 8 + cg * 2 + ni) * 512 + l * 8);
    }

    // ---- G phase: 4 kt; A=V2p pi-frags (ping-pong), B=x1-frags from LDS
#pragma unroll
    for (int ktL = 0; ktL < 4; ++ktL) {
      f16x8 xa[4];
#pragma unroll
      for (int mi = 0; mi < 4; ++mi)
        xa[mi] = *(const f16x8*)(buf + (size_t)(ktL * 8 + wrow * 4 + mi) * 512 + l * 8);
      f16x8* bb = (ktL & 1) ? bb1 : bb0;
#pragma unroll
      for (int mi = 0; mi < 4; ++mi)
#pragma unroll
        for (int ni = 0; ni < 8; ++ni)
          acc[mi][ni] = __builtin_amdgcn_mfma_f32_16x16x32_f16(bb[ni], xa[mi], acc[mi][ni], 0, 0, 0);
      if (ktL == 0) {
#pragma unroll
        for (int ni = 0; ni < 8; ++ni)
          bb0[ni] = *(const f16x8*)(bBase + (size_t)((ktg + 2) * 64 + ni) * 512);
      } else if (ktL == 1) {
#pragma unroll
        for (int ni = 0; ni < 8; ++ni)
          bb1[ni] = *(const f16x8*)(bBase + (size_t)((ktg + 3) * 64 + ni) * 512);
      }
    }
  }

  // ---- epilogue: tanh+gate in registers -> direct fragment-major x2p stores
#pragma unroll
  for (int mi = 0; mi < 4; ++mi) {
    int rt = bm * 8 + wrow * 4 + mi;
#pragma unroll
    for (int p2 = 0; p2 < 4; ++p2) {
      int kc2 = (nt0 >> 1) + p2;
      float sg2 = sigmoid_fast(g2[kc2]);
      f32x4 c0 = *(const f32x4*)(b2 + kc2 * 32 + q * 4);
      f32x4 c1 = *(const f32x4*)(b2 + kc2 * 32 + 16 + q * 4);
      f16x8 o;
#pragma unroll
      for (int r = 0; r < 4; ++r) {
        o[r]     = (_Float16)(tanh_fast(acc[mi][2 * p2][r] + c0[r]) * sg2);
        o[4 + r] = (_Float16)(tanh_fast(acc[mi][2 * p2 + 1][r] + c1[r]) * sg2);
      }
      *(f16x8*)(x2p + ((size_t)kc2 * NRT + rt) * 512 + l * 8) = o;
    }
  }
}

// ---------------- K3: fused q-network head (unchanged; pi handled by prep) ----------------
__global__ __launch_bounds__(512, 3) void k3_head(
    const _Float16* __restrict__ x2p, const _Float16* __restrict__ t1p,
    const _Float16* __restrict__ t2p,
    const float* __restrict__ bq1, const float* __restrict__ ln1g, const float* __restrict__ ln1b,
    const float* __restrict__ bq2, const float* __restrict__ ln2g, const float* __restrict__ ln2b,
    const float* __restrict__ wq3, const float* __restrict__ bq3,
    float* __restrict__ out, int NRT, int SROWS) {
  __shared__ __align__(16) _Float16 y1h[128 * 264];
  __shared__ float redA[128 * 4], redB[128 * 4];
  __shared__ float meanv[128], rstdv[128];
  int bm = blockIdx.x;
  int t = threadIdx.x, w = t >> 6, l = t & 63, q = l >> 4, l15 = l & 15;
  int wr = w >> 2, wc = w & 3;

  int gt = bm * 8;
  int slice = 0;
  if (gt >= NRT) { slice = 1; gt -= NRT; }
  int rt0 = gt + wr * 4;

  f32x4 acc[4][4] = {};
  const size_t aStep = (size_t)NRT * 512;
  const _Float16* aP = x2p + (size_t)slice * SROWS * 1024 + (size_t)rt0 * 512 + (size_t)l * 8;
  const _Float16* bP = t1p + (size_t)(wc * 4) * 512 + (size_t)l * 8;

  f16x8 a0[4], a1[4], b0[4], b1[4];
#pragma unroll
  for (int mi = 0; mi < 4; ++mi) a0[mi] = *(const f16x8*)(aP + mi * 512);
#pragma unroll
  for (int ni = 0; ni < 4; ++ni) b0[ni] = *(const f16x8*)(bP + ni * 512);
#pragma unroll
  for (int mi = 0; mi < 4; ++mi) a1[mi] = *(const f16x8*)(aP + aStep + mi * 512);
#pragma unroll
  for (int ni = 0; ni < 4; ++ni) b1[ni] = *(const f16x8*)(bP + 8192 + ni * 512);
  aP += 2 * aStep; bP += 16384;

  for (int kt = 0; kt < 32; kt += 2) {
#pragma unroll
    for (int mi = 0; mi < 4; ++mi)
#pragma unroll
      for (int ni = 0; ni < 4; ++ni)
        acc[mi][ni] = __builtin_amdgcn_mfma_f32_16x16x32_f16(a0[mi], b0[ni], acc[mi][ni], 0, 0, 0);
    if (kt < 30) {
#pragma unroll
      for (int mi = 0; mi < 4; ++mi) a0[mi] = *(const f16x8*)(aP + mi * 512);
#pragma unroll
      for (int ni = 0; ni < 4; ++ni) b0[ni] = *(const f16x8*)(bP + ni * 512);
    }
#pragma unroll
    for (int mi = 0; mi < 4; ++mi)
#pragma unroll
      for (int ni = 0; ni < 4; ++ni)
        acc[mi][ni] = __builtin_amdgcn_mfma_f32_16x16x32_f16(a1[mi], b1[ni], acc[mi][ni], 0, 0, 0);
    if (kt < 30) {
#pragma unroll
      for (int mi = 0; mi < 4; ++mi) a1[mi] = *(const f16x8*)(aP + aStep + mi * 512);
#pragma unroll
      for (int ni = 0; ni < 4; ++ni) b1[ni] = *(const f16x8*)(bP + 8192 + ni * 512);
      aP += 2 * aStep; bP += 16384;
    }
  }

#pragma unroll
  for (int ni = 0; ni < 4; ++ni) {
    int col = wc * 64 + ni * 16 + l15;
    float b = bq1[col];
#pragma unroll
    for (int mi = 0; mi < 4; ++mi)
#pragma unroll
      for (int r = 0; r < 4; ++r) acc[mi][ni][r] += b;
  }
#pragma unroll
  for (int mi = 0; mi < 4; ++mi)
#pragma unroll
    for (int r = 0; r < 4; ++r) {
      int row = wr * 64 + mi * 16 + q * 4 + r;
      float s = 0.f, sq = 0.f;
#pragma unroll
      for (int ni = 0; ni < 4; ++ni) { float v = acc[mi][ni][r]; s += v; sq += v * v; }
#pragma unroll
      for (int off = 1; off < 16; off <<= 1) { s += __shfl_xor(s, off); sq += __shfl_xor(sq, off); }
      if (l15 == 0) { redA[row * 4 + wc] = s; redB[row * 4 + wc] = sq; }
    }
  __syncthreads();
  if (t < 128) {
    float s  = redA[t * 4] + redA[t * 4 + 1] + redA[t * 4 + 2] + redA[t * 4 + 3];
    float sq = redB[t * 4] + redB[t * 4 + 1] + redB[t * 4 + 2] + redB[t * 4 + 3];
    float mean = s * (1.0f / 256.0f);
    float var = sq * (1.0f / 256.0f) - mean * mean;
    meanv[t] = mean; rstdv[t] = rsqrtf(var + 1e-5f);
  }
  __syncthreads();
#pragma unroll
  for (int mi = 0; mi < 4; ++mi)
#pragma unroll
    for (int ni = 0; ni < 4; ++ni)
#pragma unroll
      for (int r = 0; r < 4; ++r) {
        int row = wr * 64 + mi * 16 + q * 4 + r;
        int col = wc * 64 + ni * 16 + l15;
        float y = (acc[mi][ni][r] - meanv[row]) * rstdv[row] * ln1g[col] + ln1b[col];
        y = fmaxf(y, 0.f);
        y1h[row * 264 + col] = (_Float16)y;
      }
  __syncthreads();

  f32x4 a2[4][2] = {};
  for (int kt = 0; kt < 8; ++kt) {
    f16x8 af2[4];
#pragma unroll
    for (int mi = 0; mi < 4; ++mi)
      af2[mi] = *(const f16x8*)&y1h[(wr * 64 + mi * 16 + l15) * 264 + kt * 32 + q * 8];
#pragma unroll
    for (int ni = 0; ni < 2; ++ni) {
      f16x8 bf = *(const f16x8*)(t2p + (size_t)(wc * 2 + ni) * 4096 + kt * 512 + l * 8);
#pragma unroll
      for (int mi = 0; mi < 4; ++mi)
        a2[mi][ni] = __builtin_amdgcn_mfma_f32_16x16x32_f16(af2[mi], bf, a2[mi][ni], 0, 0, 0);
    }
  }
#pragma unroll
  for (int ni = 0; ni < 2; ++ni) {
    int col = wc * 32 + ni * 16 + l15;
    float b = bq2[col];
#pragma unroll
    for (int mi = 0; mi < 4; ++mi)
#pragma unroll
      for (int r = 0; r < 4; ++r) a2[mi][ni][r] += b;
  }
  __syncthreads();
#pragma unroll
  for (int mi = 0; mi < 4; ++mi)
#pragma unroll
    for (int r = 0; r < 4; ++r) {
      int row = wr * 64 + mi * 16 + q * 4 + r;
      float s = 0.f, sq = 0.f;
#pragma unroll
      for (int ni = 0; ni < 2; ++ni) { float v = a2[mi][ni][r]; s += v; sq += v * v; }
#pragma unroll
      for (int off = 1; off < 16; off <<= 1) { s += __shfl_xor(s, off); sq += __shfl_xor(sq, off); }
      if (l15 == 0) { redA[row * 4 + wc] = s; redB[row * 4 + wc] = sq; }
    }
  __syncthreads();
  if (t < 128) {
    float s  = redA[t * 4] + redA[t * 4 + 1] + redA[t * 4 + 2] + redA[t * 4 + 3];
    float sq = redB[t * 4] + redB[t * 4 + 1] + redB[t * 4 + 2] + redB[t * 4 + 3];
    float mean = s * (1.0f / 128.0f);
    float var = sq * (1.0f / 128.0f) - mean * mean;
    meanv[t] = mean; rstdv[t] = rsqrtf(var + 1e-5f);
  }
  __syncthreads();
#pragma unroll
  for (int mi = 0; mi < 4; ++mi)
#pragma unroll
    for (int r = 0; r < 4; ++r) {
      int row = wr * 64 + mi * 16 + q * 4 + r;
      float pr = 0.f;
#pragma unroll
      for (int ni = 0; ni < 2; ++ni) {
        int col = wc * 32 + ni * 16 + l15;
        float y = (a2[mi][ni][r] - meanv[row]) * rstdv[row] * ln2g[col] + ln2b[col];
        y = fmaxf(y, 0.f);
        pr += y * wq3[col];
      }
#pragma unroll
      for (int off = 1; off < 16; off <<= 1) pr += __shfl_xor(pr, off);
      if (l15 == 0) redA[row * 4 + wc] = pr;
    }
  __syncthreads();
  if (t < 128)
    out[bm * 128 + t] = redA[t * 4] + redA[t * 4 + 1] + redA[t * 4 + 2] + redA[t * 4 + 3] + bq3[0];
}

// ---------------- launcher ----------------
extern "C" void kernel_launch(void* const* d_in, const int* in_sizes, int n_in,
                              void* d_out, int out_size, void* d_ws, size_t ws_size,
                              hipStream_t stream) {
  const float* state  = (const float*)d_in[0];
  const float* action = (const float*)d_in[1];
  const float* W1  = (const float*)d_in[2];
  const float* b1  = (const float*)d_in[3];
  const float* g1  = (const float*)d_in[4];
  const float* W2  = (const float*)d_in[5];
  const float* b2  = (const float*)d_in[6];
  const float* g2  = (const float*)d_in[7];
  const float* Wq1 = (const float*)d_in[8];
  const float* bq1 = (const float*)d_in[9];
  const float* ln1g = (const float*)d_in[10];
  const float* ln1b = (const float*)d_in[11];
  const float* Wq2 = (const float*)d_in[12];
  const float* bq2 = (const float*)d_in[13];
  const float* ln2g = (const float*)d_in[14];
  const float* ln2b = (const float*)d_in[15];
  const float* Wq3 = (const float*)d_in[16];
  const float* bq3 = (const float*)d_in[17];
  int B = in_sizes[0] / 24;

  char* ws = (char*)d_ws;
  _Float16* V1p = (_Float16*)(ws);
  _Float16* V2p = (_Float16*)(ws + 65536);
  _Float16* T1p = (_Float16*)(ws + 65536 + 2097152);
  _Float16* T2p = (_Float16*)(ws + 65536 + 2097152 + 524288);
  size_t woff = (65536 + 2097152 + 524288 + 65536 + 4095) & ~(size_t)4095;

  size_t avail = ws_size > woff ? ws_size - woff : 0;
  int S, G;
  if (avail >= (size_t)32768 * 2048 * 2) {      // x2 only: 2 slices of S rows
    S = 32768; G = 2;
  } else {
    long rows = (long)(avail / 2048);
    if (rows > 32768) rows = 32768;
    rows &= ~127L;
    if (rows < 128) rows = 128;
    S = (int)rows; G = 1;
  }
  _Float16* x2 = (_Float16*)(ws + woff);
  int NRT = S / 16;

  prep_weights<<<2656, 256, 0, stream>>>(W1, W2, Wq1, Wq2, V1p, V2p, T1p, T2p);

  int nsl = (B + S - 1) / S;
  for (int i = 0; i < nsl; ++i) {
    int r0 = i * S;
    int Sc = S < (B - r0) ? S : (B - r0);
    int nbm = Sc / 128;
    k12_fused<<<dim3(2 * nbm), 512, 0, stream>>>(state, action, V1p, b1, g1,
                                                 V2p, b2, g2,
                                                 x2 + (size_t)(i % G) * S * 1024, r0, NRT);
    if (i % G == G - 1 || i == nsl - 1) {
      int gstart = (i - i % G) * S;
      int nrows = r0 + Sc - gstart;
      k3_head<<<dim3(nrows / 128), 512, 0, stream>>>(x2, T1p, T2p, bq1, ln1g, ln1b,
                                                     bq2, ln2g, ln2b, Wq3, bq3,
                                                     (float*)d_out + gstart, NRT, S);
    }
  }
}

// Round 12
// 599.782 us; speedup vs baseline: 1.0615x; 1.0094x over previous
//
#include <hip/hip_runtime.h>
#include <hip/hip_bf16.h>

typedef _Float16 f16x8 __attribute__((ext_vector_type(8)));
typedef _Float16 f16x4 __attribute__((ext_vector_type(4)));
typedef float f32x4 __attribute__((ext_vector_type(4)));

__device__ __forceinline__ float tanh_fast(float x) {
  float e = __expf(2.0f * x);
  return 1.0f - 2.0f * __builtin_amdgcn_rcpf(e + 1.0f);
}
__device__ __forceinline__ float sigmoid_fast(float x) {
  return __builtin_amdgcn_rcpf(1.0f + __expf(-x));
}

// ---------------- K0: weight prep ----------------
// Fragment tiles of 512 hw. PI k-order (W2, Wq1): lane l elem j holds
// B[k = kt*32 + pi(q,j)][col = nt*16 + l15], pi(q,j) = q*4 + (j&3) + 16*(j>>2).
// Plain k-order (Wq2, W1): k = q*8 + j.
// V2p tile = kt*64 + nt; T1p tile = kt*16 + nt; T2p tile = nt*8 + kt.
__global__ __launch_bounds__(256) void prep_weights(
    const float* __restrict__ W1, const float* __restrict__ W2,
    const float* __restrict__ Wq1, const float* __restrict__ Wq2,
    _Float16* __restrict__ V1p, _Float16* __restrict__ V2p,
    _Float16* __restrict__ T1p, _Float16* __restrict__ T2p) {
  __shared__ float S[32 * 33];
  int b = blockIdx.x, t = threadIdx.x;
  if (b < 2624) {
    const float* in; _Float16* out; int N, nc0, tile, use_pi;
    if (b < 2048) {        // W2 [32][1024][32]: h, ntl, kt  (PI)
      int h = b >> 6, rem = b & 63, ntl = rem >> 5, kt = rem & 31;
      in = W2 + (size_t)h * 32768 + (size_t)kt * 32 * 32;
      N = 32; nc0 = ntl * 16;
      out = V2p; tile = kt * 64 + (h * 2 + ntl); use_pi = 1;
    } else if (b < 2560) { // Wq1 [1024][256]  (PI)
      int i = b - 2048, nt = i >> 5, kt = i & 31;
      in = Wq1 + (size_t)kt * 32 * 256; N = 256; nc0 = nt * 16;
      out = T1p; tile = kt * 16 + nt; use_pi = 1;
    } else {               // Wq2 [256][128]  (plain)
      int i = b - 2560, nt = i >> 3, kt = i & 7;
      in = Wq2 + (size_t)kt * 32 * 128; N = 128; nc0 = nt * 16;
      out = T2p; tile = nt * 8 + kt; use_pi = 0;
    }
    if (t < 128) {
      int r = t >> 2, c4 = (t & 3) * 4;
      const float4 v = *(const float4*)(in + (size_t)r * N + nc0 + c4);
      S[r * 17 + c4 + 0] = v.x; S[r * 17 + c4 + 1] = v.y;
      S[r * 17 + c4 + 2] = v.z; S[r * 17 + c4 + 3] = v.w;
    }
    __syncthreads();
    if (t < 128) {
      int w2 = t >> 6, l = t & 63, q = l >> 4, l15 = l & 15;
      f16x4 o;
#pragma unroll
      for (int jj = 0; jj < 4; ++jj) {
        int kl = use_pi ? (q * 4 + jj + w2 * 16) : (q * 8 + w2 * 4 + jj);
        o[jj] = (_Float16)S[kl * 17 + l15];
      }
      *(f16x4*)(out + (size_t)tile * 512 + l * 8 + w2 * 4) = o;
    }
  } else {                 // W1 [32][32][32]: one block per head h (plain)
    int h = b - 2624;
    const float* in = W1 + h * 1024;
    int cc = t & 31, rr8 = t >> 5;
#pragma unroll
    for (int p = 0; p < 4; ++p) {
      int r = rr8 + p * 8;
      S[cc * 33 + r] = in[r * 32 + cc];
    }
    __syncthreads();
    if (t < 128) {
      int ntl = t >> 6, l = t & 63, q = l >> 4, l15 = l & 15;
      f16x8 o;
#pragma unroll
      for (int j = 0; j < 8; ++j)
        o[j] = (_Float16)S[(ntl * 16 + l15) * 33 + q * 8 + j];
      *(f16x8*)(V1p + (size_t)(h * 2 + ntl) * 512 + l * 8) = o;
    }
  }
}

// ---------------- K12: fused ripple1+ripple2, 256-thread blocks ----------------
// Block = 128 rows x 256 cols, 4 waves (wrow=w&1 row half, cg2=w>>1 col half).
// 2 blocks/CU co-resident -> cross-block overlap of barrier/R stalls.
// R(kc+1) placed between G-halves; B-stream uniform kt ping-pong (4+4 regs);
// kc loop fully unrolled.
__global__ __launch_bounds__(256, 2) void k12_fused(
    const float* __restrict__ state, const float* __restrict__ action,
    const _Float16* __restrict__ v1p, const float* __restrict__ b1,
    const float* __restrict__ g1,
    const _Float16* __restrict__ v2p, const float* __restrict__ b2,
    const float* __restrict__ g2,
    _Float16* __restrict__ x2p, int gro, int NRT) {
  __shared__ __align__(16) _Float16 SA[128 * 40];        // 10 KB
  __shared__ __align__(16) _Float16 XF[2 * 16384];       // 64 KB frag dbuf
  int g = blockIdx.x;
  int bn2 = g & 3, bm = g >> 2;
  int t = threadIdx.x, w = t >> 6, l = t & 63, q = l >> 4, l15 = l & 15;
  int wrow = w & 1, cg2 = w >> 1;
  int m0 = bm * 128;

  {  // stage sa tile [128][32] fp16, stride 40; 2 threads/row
    int r = t >> 1, half = t & 1;
    size_t grow = (size_t)(gro + m0 + r);
    float v[16];
    if (half == 0) {
      const float4* sp = (const float4*)(state + grow * 24);
      ((float4*)v)[0] = sp[0]; ((float4*)v)[1] = sp[1];
      ((float4*)v)[2] = sp[2]; ((float4*)v)[3] = sp[3];
    } else {
      const float4* sp = (const float4*)(state + grow * 24 + 16);
      ((float4*)v)[0] = sp[0]; ((float4*)v)[1] = sp[1];
      const float4* ap = (const float4*)(action + grow * 8);
      ((float4*)v)[2] = ap[0]; ((float4*)v)[3] = ap[1];
    }
    f16x8 h0, h1;
#pragma unroll
    for (int j = 0; j < 8; ++j) { h0[j] = (_Float16)v[j]; h1[j] = (_Float16)v[8 + j]; }
    *(f16x8*)&SA[r * 40 + half * 16] = h0;
    *(f16x8*)&SA[r * 40 + half * 16 + 8] = h1;
  }
  __syncthreads();

  // loop-invariant sa fragments (B operand of R phase)
  f16x8 asa[4];
#pragma unroll
  for (int p = 0; p < 4; ++p)
    asa[p] = *(const f16x8*)&SA[((wrow * 4 + p) * 16 + l15) * 40 + q * 8];

  const int nt0 = bn2 * 16 + cg2 * 8;
  const _Float16* bBase = v2p + (size_t)nt0 * 512 + (size_t)l * 8;
  f32x4 acc[4][8] = {};

  // R phase: wave produces x1 chunk rows wrow*64..+63, cols cg2*64..+63
  // (= ktL tiles 2*cg2, 2*cg2+1), processed in 2 column halves to bound regs.
  auto Rphase = [&](int kcn) {
#pragma unroll
    for (int e = 0; e < 2; ++e) {
      f16x8 rb0 = *(const f16x8*)(v1p + (size_t)(kcn * 8 + cg2 * 4 + 2 * e) * 512 + l * 8);
      f16x8 rb1 = *(const f16x8*)(v1p + (size_t)(kcn * 8 + cg2 * 4 + 2 * e + 1) * 512 + l * 8);
      float sg = sigmoid_fast(g1[kcn * 4 + cg2 * 2 + e]);
      const float* bp = b1 + kcn * 128 + cg2 * 64 + e * 32 + q * 4;
      f32x4 bs0 = *(const f32x4*)(bp);
      f32x4 bs1 = *(const f32x4*)(bp + 16);
      _Float16* bw = XF + ((kcn & 1) * 16384);
#pragma unroll
      for (int p = 0; p < 4; ++p) {
        f32x4 d0 = {}, d1 = {};
        d0 = __builtin_amdgcn_mfma_f32_16x16x32_f16(rb0, asa[p], d0, 0, 0, 0);
        d1 = __builtin_amdgcn_mfma_f32_16x16x32_f16(rb1, asa[p], d1, 0, 0, 0);
        f16x8 o;
#pragma unroll
        for (int r = 0; r < 4; ++r) {
          o[r]     = (_Float16)(tanh_fast(d0[r] + bs0[r]) * sg);
          o[4 + r] = (_Float16)(tanh_fast(d1[r] + bs1[r]) * sg);
        }
        *(f16x8*)(bw + (size_t)((2 * cg2 + e) * 8 + wrow * 4 + p) * 512 + l * 8) = o;
      }
    }
  };

  // prologue: B stream s=0,1 (kt0 halves) + R(0)
  f16x8 bb0[4], bb1v[4];
#pragma unroll
  for (int n2 = 0; n2 < 4; ++n2)
    bb0[n2] = *(const f16x8*)(bBase + (size_t)n2 * 512);
#pragma unroll
  for (int n2 = 0; n2 < 4; ++n2)
    bb1v[n2] = *(const f16x8*)(bBase + (size_t)(4 + n2) * 512);
  Rphase(0);
  __syncthreads();

#pragma unroll
  for (int kc = 0; kc < 8; ++kc) {
    const _Float16* buf = XF + ((kc & 1) * 16384);
#pragma unroll
    for (int j = 0; j < 4; ++j) {
      if (j == 2 && kc < 7) Rphase(kc + 1);
      int kt = kc * 4 + j;
      f16x8 xa[4];
#pragma unroll
      for (int mi = 0; mi < 4; ++mi)
        xa[mi] = *(const f16x8*)(buf + (size_t)(j * 8 + wrow * 4 + mi) * 512 + l * 8);
      // half 0 (ni 0..3)
#pragma unroll
      for (int mi = 0; mi < 4; ++mi)
#pragma unroll
        for (int n2 = 0; n2 < 4; ++n2)
          acc[mi][n2] = __builtin_amdgcn_mfma_f32_16x16x32_f16(bb0[n2], xa[mi], acc[mi][n2], 0, 0, 0);
      if (kt < 31) {
#pragma unroll
        for (int n2 = 0; n2 < 4; ++n2)
          bb0[n2] = *(const f16x8*)(bBase + (size_t)((kt + 1) * 64 + n2) * 512);
      }
      // half 1 (ni 4..7)
#pragma unroll
      for (int mi = 0; mi < 4; ++mi)
#pragma unroll
        for (int n2 = 0; n2 < 4; ++n2)
          acc[mi][4 + n2] = __builtin_amdgcn_mfma_f32_16x16x32_f16(bb1v[n2], xa[mi], acc[mi][4 + n2], 0, 0, 0);
      if (kt < 31) {
#pragma unroll
        for (int n2 = 0; n2 < 4; ++n2)
          bb1v[n2] = *(const f16x8*)(bBase + (size_t)((kt + 1) * 64 + 4 + n2) * 512);
      }
    }
    __syncthreads();
  }

  // epilogue: tanh+gate in registers -> direct fragment-major x2p stores
#pragma unroll
  for (int mi = 0; mi < 4; ++mi) {
    int rt = bm * 8 + wrow * 4 + mi;
#pragma unroll
    for (int p2 = 0; p2 < 4; ++p2) {
      int kc2 = (nt0 >> 1) + p2;
      float sg2 = sigmoid_fast(g2[kc2]);
      f32x4 c0 = *(const f32x4*)(b2 + kc2 * 32 + q * 4);
      f32x4 c1 = *(const f32x4*)(b2 + kc2 * 32 + 16 + q * 4);
      f16x8 o;
#pragma unroll
      for (int r = 0; r < 4; ++r) {
        o[r]     = (_Float16)(tanh_fast(acc[mi][2 * p2][r] + c0[r]) * sg2);
        o[4 + r] = (_Float16)(tanh_fast(acc[mi][2 * p2 + 1][r] + c1[r]) * sg2);
      }
      *(f16x8*)(x2p + ((size_t)kc2 * NRT + rt) * 512 + l * 8) = o;
    }
  }
}

// ---------------- K3: fused q-network head (unchanged) ----------------
__global__ __launch_bounds__(512, 3) void k3_head(
    const _Float16* __restrict__ x2p, const _Float16* __restrict__ t1p,
    const _Float16* __restrict__ t2p,
    const float* __restrict__ bq1, const float* __restrict__ ln1g, const float* __restrict__ ln1b,
    const float* __restrict__ bq2, const float* __restrict__ ln2g, const float* __restrict__ ln2b,
    const float* __restrict__ wq3, const float* __restrict__ bq3,
    float* __restrict__ out, int NRT, int SROWS) {
  __shared__ __align__(16) _Float16 y1h[128 * 264];
  __shared__ float redA[128 * 4], redB[128 * 4];
  __shared__ float meanv[128], rstdv[128];
  int bm = blockIdx.x;
  int t = threadIdx.x, w = t >> 6, l = t & 63, q = l >> 4, l15 = l & 15;
  int wr = w >> 2, wc = w & 3;

  int gt = bm * 8;
  int slice = 0;
  if (gt >= NRT) { slice = 1; gt -= NRT; }
  int rt0 = gt + wr * 4;

  f32x4 acc[4][4] = {};
  const size_t aStep = (size_t)NRT * 512;
  const _Float16* aP = x2p + (size_t)slice * SROWS * 1024 + (size_t)rt0 * 512 + (size_t)l * 8;
  const _Float16* bP = t1p + (size_t)(wc * 4) * 512 + (size_t)l * 8;

  f16x8 a0[4], a1[4], b0[4], b1[4];
#pragma unroll
  for (int mi = 0; mi < 4; ++mi) a0[mi] = *(const f16x8*)(aP + mi * 512);
#pragma unroll
  for (int ni = 0; ni < 4; ++ni) b0[ni] = *(const f16x8*)(bP + ni * 512);
#pragma unroll
  for (int mi = 0; mi < 4; ++mi) a1[mi] = *(const f16x8*)(aP + aStep + mi * 512);
#pragma unroll
  for (int ni = 0; ni < 4; ++ni) b1[ni] = *(const f16x8*)(bP + 8192 + ni * 512);
  aP += 2 * aStep; bP += 16384;

  for (int kt = 0; kt < 32; kt += 2) {
#pragma unroll
    for (int mi = 0; mi < 4; ++mi)
#pragma unroll
      for (int ni = 0; ni < 4; ++ni)
        acc[mi][ni] = __builtin_amdgcn_mfma_f32_16x16x32_f16(a0[mi], b0[ni], acc[mi][ni], 0, 0, 0);
    if (kt < 30) {
#pragma unroll
      for (int mi = 0; mi < 4; ++mi) a0[mi] = *(const f16x8*)(aP + mi * 512);
#pragma unroll
      for (int ni = 0; ni < 4; ++ni) b0[ni] = *(const f16x8*)(bP + ni * 512);
    }
#pragma unroll
    for (int mi = 0; mi < 4; ++mi)
#pragma unroll
      for (int ni = 0; ni < 4; ++ni)
        acc[mi][ni] = __builtin_amdgcn_mfma_f32_16x16x32_f16(a1[mi], b1[ni], acc[mi][ni], 0, 0, 0);
    if (kt < 30) {
#pragma unroll
      for (int mi = 0; mi < 4; ++mi) a1[mi] = *(const f16x8*)(aP + aStep + mi * 512);
#pragma unroll
      for (int ni = 0; ni < 4; ++ni) b1[ni] = *(const f16x8*)(bP + 8192 + ni * 512);
      aP += 2 * aStep; bP += 16384;
    }
  }

#pragma unroll
  for (int ni = 0; ni < 4; ++ni) {
    int col = wc * 64 + ni * 16 + l15;
    float b = bq1[col];
#pragma unroll
    for (int mi = 0; mi < 4; ++mi)
#pragma unroll
      for (int r = 0; r < 4; ++r) acc[mi][ni][r] += b;
  }
#pragma unroll
  for (int mi = 0; mi < 4; ++mi)
#pragma unroll
    for (int r = 0; r < 4; ++r) {
      int row = wr * 64 + mi * 16 + q * 4 + r;
      float s = 0.f, sq = 0.f;
#pragma unroll
      for (int ni = 0; ni < 4; ++ni) { float v = acc[mi][ni][r]; s += v; sq += v * v; }
#pragma unroll
      for (int off = 1; off < 16; off <<= 1) { s += __shfl_xor(s, off); sq += __shfl_xor(sq, off); }
      if (l15 == 0) { redA[row * 4 + wc] = s; redB[row * 4 + wc] = sq; }
    }
  __syncthreads();
  if (t < 128) {
    float s  = redA[t * 4] + redA[t * 4 + 1] + redA[t * 4 + 2] + redA[t * 4 + 3];
    float sq = redB[t * 4] + redB[t * 4 + 1] + redB[t * 4 + 2] + redB[t * 4 + 3];
    float mean = s * (1.0f / 256.0f);
    float var = sq * (1.0f / 256.0f) - mean * mean;
    meanv[t] = mean; rstdv[t] = rsqrtf(var + 1e-5f);
  }
  __syncthreads();
#pragma unroll
  for (int mi = 0; mi < 4; ++mi)
#pragma unroll
    for (int ni = 0; ni < 4; ++ni)
#pragma unroll
      for (int r = 0; r < 4; ++r) {
        int row = wr * 64 + mi * 16 + q * 4 + r;
        int col = wc * 64 + ni * 16 + l15;
        float y = (acc[mi][ni][r] - meanv[row]) * rstdv[row] * ln1g[col] + ln1b[col];
        y = fmaxf(y, 0.f);
        y1h[row * 264 + col] = (_Float16)y;
      }
  __syncthreads();

  f32x4 a2[4][2] = {};
  for (int kt = 0; kt < 8; ++kt) {
    f16x8 af2[4];
#pragma unroll
    for (int mi = 0; mi < 4; ++mi)
      af2[mi] = *(const f16x8*)&y1h[(wr * 64 + mi * 16 + l15) * 264 + kt * 32 + q * 8];
#pragma unroll
    for (int ni = 0; ni < 2; ++ni) {
      f16x8 bf = *(const f16x8*)(t2p + (size_t)(wc * 2 + ni) * 4096 + kt * 512 + l * 8);
#pragma unroll
      for (int mi = 0; mi < 4; ++mi)
        a2[mi][ni] = __builtin_amdgcn_mfma_f32_16x16x32_f16(af2[mi], bf, a2[mi][ni], 0, 0, 0);
    }
  }
#pragma unroll
  for (int ni = 0; ni < 2; ++ni) {
    int col = wc * 32 + ni * 16 + l15;
    float b = bq2[col];
#pragma unroll
    for (int mi = 0; mi < 4; ++mi)
#pragma unroll
      for (int r = 0; r < 4; ++r) a2[mi][ni][r] += b;
  }
  __syncthreads();
#pragma unroll
  for (int mi = 0; mi < 4; ++mi)
#pragma unroll
    for (int r = 0; r < 4; ++r) {
      int row = wr * 64 + mi * 16 + q * 4 + r;
      float s = 0.f, sq = 0.f;
#pragma unroll
      for (int ni = 0; ni < 2; ++ni) { float v = a2[mi][ni][r]; s += v; sq += v * v; }
#pragma unroll
      for (int off = 1; off < 16; off <<= 1) { s += __shfl_xor(s, off); sq += __shfl_xor(sq, off); }
      if (l15 == 0) { redA[row * 4 + wc] = s; redB[row * 4 + wc] = sq; }
    }
  __syncthreads();
  if (t < 128) {
    float s  = redA[t * 4] + redA[t * 4 + 1] + redA[t * 4 + 2] + redA[t * 4 + 3];
    float sq = redB[t * 4] + redB[t * 4 + 1] + redB[t * 4 + 2] + redB[t * 4 + 3];
    float mean = s * (1.0f / 128.0f);
    float var = sq * (1.0f / 128.0f) - mean * mean;
    meanv[t] = mean; rstdv[t] = rsqrtf(var + 1e-5f);
  }
  __syncthreads();
#pragma unroll
  for (int mi = 0; mi < 4; ++mi)
#pragma unroll
    for (int r = 0; r < 4; ++r) {
      int row = wr * 64 + mi * 16 + q * 4 + r;
      float pr = 0.f;
#pragma unroll
      for (int ni = 0; ni < 2; ++ni) {
        int col = wc * 32 + ni * 16 + l15;
        float y = (a2[mi][ni][r] - meanv[row]) * rstdv[row] * ln2g[col] + ln2b[col];
        y = fmaxf(y, 0.f);
        pr += y * wq3[col];
      }
#pragma unroll
      for (int off = 1; off < 16; off <<= 1) pr += __shfl_xor(pr, off);
      if (l15 == 0) redA[row * 4 + wc] = pr;
    }
  __syncthreads();
  if (t < 128)
    out[bm * 128 + t] = redA[t * 4] + redA[t * 4 + 1] + redA[t * 4 + 2] + redA[t * 4 + 3] + bq3[0];
}

// ---------------- launcher ----------------
extern "C" void kernel_launch(void* const* d_in, const int* in_sizes, int n_in,
                              void* d_out, int out_size, void* d_ws, size_t ws_size,
                              hipStream_t stream) {
  const float* state  = (const float*)d_in[0];
  const float* action = (const float*)d_in[1];
  const float* W1  = (const float*)d_in[2];
  const float* b1  = (const float*)d_in[3];
  const float* g1  = (const float*)d_in[4];
  const float* W2  = (const float*)d_in[5];
  const float* b2  = (const float*)d_in[6];
  const float* g2  = (const float*)d_in[7];
  const float* Wq1 = (const float*)d_in[8];
  const float* bq1 = (const float*)d_in[9];
  const float* ln1g = (const float*)d_in[10];
  const float* ln1b = (const float*)d_in[11];
  const float* Wq2 = (const float*)d_in[12];
  const float* bq2 = (const float*)d_in[13];
  const float* ln2g = (const float*)d_in[14];
  const float* ln2b = (const float*)d_in[15];
  const float* Wq3 = (const float*)d_in[16];
  const float* bq3 = (const float*)d_in[17];
  int B = in_sizes[0] / 24;

  char* ws = (char*)d_ws;
  _Float16* V1p = (_Float16*)(ws);
  _Float16* V2p = (_Float16*)(ws + 65536);
  _Float16* T1p = (_Float16*)(ws + 65536 + 2097152);
  _Float16* T2p = (_Float16*)(ws + 65536 + 2097152 + 524288);
  size_t woff = (65536 + 2097152 + 524288 + 65536 + 4095) & ~(size_t)4095;

  size_t avail = ws_size > woff ? ws_size - woff : 0;
  long rows = (long)(avail / 2048);     // x2 fp16 1024-wide, single slice (G=1: L3-hot for k3)
  if (rows > 32768) rows = 32768;
  rows &= ~127L;
  if (rows < 128) rows = 128;
  int S = (int)rows;
  _Float16* x2 = (_Float16*)(ws + woff);
  int NRT = S / 16;

  prep_weights<<<2656, 256, 0, stream>>>(W1, W2, Wq1, Wq2, V1p, V2p, T1p, T2p);

  for (int r0 = 0; r0 < B; r0 += S) {
    int Sc = S < (B - r0) ? S : (B - r0);
    int nbm = Sc / 128;
    k12_fused<<<dim3(4 * nbm), 256, 0, stream>>>(state, action, V1p, b1, g1,
                                                 V2p, b2, g2, x2, r0, NRT);
    k3_head<<<dim3(Sc / 128), 512, 0, stream>>>(x2, T1p, T2p, bq1, ln1g, ln1b,
                                                bq2, ln2g, ln2b, Wq3, bq3,
                                                (float*)d_out + r0, NRT, S);
  }
}